// Round 1
// baseline (365.103 us; speedup 1.0000x reference)
//
#include <hip/hip_runtime.h>
#include <hip/hip_bf16.h>

#define G_COUNT 2048
#define IMG_W 128
#define IMG_H 128
#define ALPHA_THR (1.0f / 255.0f)
#define T_THR 1e-4f
#define ALPHA_MAX 0.99f

// ---------------- Kernel 1: stable depth sort + gather into sorted SoA ----------------
// ws layout:
//   [0)        float4 pc[2048]   : {mx, my, conic_a, conic_b}       (32 KB)
//   [32768)    float4 cc[2048]   : {conic_c, col_r, col_g, col_b}   (32 KB)
//   [65536)    float  op[2048]   : opacity                          (8 KB)

__global__ __launch_bounds__(1024)
void sort_gather_kernel(const float* __restrict__ means2d,
                        const float* __restrict__ conics,
                        const float* __restrict__ colors,
                        const float* __restrict__ opac,
                        const float* __restrict__ depths,
                        float4* __restrict__ pc,
                        float4* __restrict__ cc,
                        float* __restrict__ opw) {
    __shared__ unsigned long long keys[G_COUNT];
    const int t = threadIdx.x;

    // depths are all positive (0.1..10): raw float bits preserve order.
    for (int i = t; i < G_COUNT; i += 1024) {
        unsigned u = __float_as_uint(depths[i]);
        keys[i] = ((unsigned long long)u << 32) | (unsigned)i;  // stable tiebreak by idx
    }
    __syncthreads();

    // Bitonic sort, 1024 threads handle 1024 compare-exchange pairs per stage.
    for (int k = 2; k <= G_COUNT; k <<= 1) {
        for (int j = k >> 1; j > 0; j >>= 1) {
            int i = ((t & ~(j - 1)) << 1) | (t & (j - 1));
            int ixj = i | j;
            bool up = ((i & k) == 0);
            unsigned long long a = keys[i];
            unsigned long long b = keys[ixj];
            if ((a > b) == up) {  // out of order for the desired direction
                keys[i] = b;
                keys[ixj] = a;
            }
            __syncthreads();
        }
    }

    // Gather into sorted SoA.
    for (int i = t; i < G_COUNT; i += 1024) {
        int idx = (int)(keys[i] & 0xffffffffULL);
        float mx = means2d[2 * idx + 0];
        float my = means2d[2 * idx + 1];
        float ca = conics[3 * idx + 0];
        float cb = conics[3 * idx + 1];
        float cc_ = conics[3 * idx + 2];
        float r = colors[3 * idx + 0];
        float g = colors[3 * idx + 1];
        float b = colors[3 * idx + 2];
        pc[i] = make_float4(mx, my, ca, cb);
        cc[i] = make_float4(cc_, r, g, b);
        opw[i] = opac[idx];
    }
}

// ---------------- Kernel 2: per-pixel front-to-back compositing ----------------
// 256 blocks x 64 threads; each block = one 8x8 pixel tile (1 wave).
__global__ __launch_bounds__(64)
void raster_kernel(const float4* __restrict__ pc,
                   const float4* __restrict__ cc,
                   const float* __restrict__ opw,
                   float* __restrict__ out) {
    const int tile = blockIdx.x;          // 16 x 16 tiles of 8x8
    const int tx = tile & 15;
    const int ty = tile >> 4;
    const int lx = threadIdx.x & 7;
    const int ly = threadIdx.x >> 3;
    const int pxi = tx * 8 + lx;
    const int pyi = ty * 8 + ly;
    const float px = (float)pxi + 0.5f;
    const float py = (float)pyi + 0.5f;

    float T = 1.0f;
    float accr = 0.0f, accg = 0.0f, accb = 0.0f;

    for (int i = 0; i < G_COUNT; ++i) {
        float4 p = pc[i];   // {mx, my, a, b} — wave-uniform address
        float4 c = cc[i];   // {c, r, g, b}
        float o = opw[i];

        float dx = px - p.x;
        float dy = py - p.y;
        float sigma = 0.5f * (p.z * dx * dx + c.x * dy * dy) + p.w * dx * dy;
        float alpha = fminf(o * __expf(-sigma), ALPHA_MAX);
        bool zero = (sigma < 0.0f) || (alpha < ALPHA_THR);
        alpha = zero ? 0.0f : alpha;

        float om = 1.0f - alpha;
        float Tn = T * om;
        float w = (Tn >= T_THR) ? alpha * T : 0.0f;
        accr = fmaf(w, c.y, accr);
        accg = fmaf(w, c.z, accg);
        accb = fmaf(w, c.w, accb);
        T = Tn;

        // Wave-wide early exit: once every lane's T < T_THR nothing can
        // contribute any more (one_m <= 1 keeps T below threshold forever).
        if (__ballot(T >= T_THR) == 0ULL) break;
    }

    float* o = out + ((size_t)pyi * IMG_W + pxi) * 3;
    o[0] = accr;
    o[1] = accg;
    o[2] = accb;
}

extern "C" void kernel_launch(void* const* d_in, const int* in_sizes, int n_in,
                              void* d_out, int out_size, void* d_ws, size_t ws_size,
                              hipStream_t stream) {
    const float* means2d = (const float*)d_in[0];
    const float* conics  = (const float*)d_in[1];
    const float* colors  = (const float*)d_in[2];
    const float* opac    = (const float*)d_in[3];
    const float* depths  = (const float*)d_in[4];
    float* out = (float*)d_out;

    char* ws = (char*)d_ws;
    float4* pc  = (float4*)(ws);
    float4* cc  = (float4*)(ws + 32768);
    float*  opw = (float*)(ws + 65536);

    sort_gather_kernel<<<1, 1024, 0, stream>>>(means2d, conics, colors, opac, depths,
                                               pc, cc, opw);
    raster_kernel<<<256, 64, 0, stream>>>(pc, cc, opw, out);
}

// Round 2
// 56.117 us; speedup vs baseline: 6.5061x; 6.5061x over previous
//
#include <hip/hip_runtime.h>
#include <hip/hip_bf16.h>

#define G_COUNT 2048
#define IMG_W 128
#define IMG_H 128
#define ALPHA_THR (1.0f / 255.0f)
#define T_THR 1e-4f
#define ALPHA_MAX 0.99f

// ws layout:
//   [0)      float4 pc[2048] : {mx, my, conic_a, conic_b}      (32 KB)
//   [32768)  float4 cc[2048] : {conic_c, col_r, col_g, col_b}  (32 KB)
//   [65536)  float2 ow[2048] : {opacity, cull_radius^2}        (16 KB)

// ---------------- Kernel 1: stable depth sort + gather + radius precompute ----------------
__global__ __launch_bounds__(1024)
void sort_gather_kernel(const float* __restrict__ means2d,
                        const float* __restrict__ conics,
                        const float* __restrict__ colors,
                        const float* __restrict__ opac,
                        const float* __restrict__ depths,
                        float4* __restrict__ pc,
                        float4* __restrict__ cc,
                        float2* __restrict__ ow) {
    __shared__ unsigned long long keys[G_COUNT];
    const int t = threadIdx.x;

    // depths all positive (0.1..10): raw float bits preserve order.
    for (int i = t; i < G_COUNT; i += 1024) {
        unsigned u = __float_as_uint(depths[i]);
        keys[i] = ((unsigned long long)u << 32) | (unsigned)i;  // stable tiebreak
    }
    __syncthreads();

    for (int k = 2; k <= G_COUNT; k <<= 1) {
        for (int j = k >> 1; j > 0; j >>= 1) {
            int i = ((t & ~(j - 1)) << 1) | (t & (j - 1));
            int ixj = i | j;
            bool up = ((i & k) == 0);
            unsigned long long a = keys[i];
            unsigned long long b = keys[ixj];
            if ((a > b) == up) {
                keys[i] = b;
                keys[ixj] = a;
            }
            __syncthreads();
        }
    }

    for (int i = t; i < G_COUNT; i += 1024) {
        int idx = (int)(keys[i] & 0xffffffffULL);
        float mx = means2d[2 * idx + 0];
        float my = means2d[2 * idx + 1];
        float ca = conics[3 * idx + 0];
        float cb = conics[3 * idx + 1];
        float c2 = conics[3 * idx + 2];
        float r = colors[3 * idx + 0];
        float g = colors[3 * idx + 1];
        float b = colors[3 * idx + 2];
        float o = opac[idx];

        // Conservative cull radius: sigma >= 0.5*lmin*|d|^2, so |d|^2 > 2*smax/lmin
        // implies alpha < 1/255. 2% inflation for fp slop.
        float half_tr = 0.5f * (ca + c2);
        float hd = 0.5f * (ca - c2);
        float lmin = half_tr - sqrtf(hd * hd + cb * cb);
        float smax = logf(255.0f * o);   // o >= 0.05 -> positive
        float r2 = (lmin > 1e-12f) ? (2.04f * smax / lmin) : 1e30f;

        pc[i] = make_float4(mx, my, ca, cb);
        cc[i] = make_float4(c2, r, g, b);
        ow[i] = make_float2(o, r2);
    }
}

// ---------------- Kernel 2: cull+compact into LDS, then composite ----------------
// 256 blocks x 64 threads; block = one 8x8 pixel tile (1 wave).
__global__ __launch_bounds__(64)
void raster_kernel(const float4* __restrict__ pc,
                   const float4* __restrict__ cc,
                   const float2* __restrict__ ow,
                   float* __restrict__ out) {
    __shared__ float4 s_pc[G_COUNT];
    __shared__ float4 s_cc[G_COUNT];
    __shared__ float  s_op[G_COUNT];

    const int tile = blockIdx.x;          // 16 x 16 tiles of 8x8
    const int tx = tile & 15;
    const int ty = tile >> 4;
    const int lane = threadIdx.x;
    const int lx = lane & 7;
    const int ly = lane >> 3;
    const int pxi = tx * 8 + lx;
    const int pyi = ty * 8 + ly;
    const float px = (float)pxi + 0.5f;
    const float py = (float)pyi + 0.5f;

    // Tile pixel-center bounds.
    const float bx0 = (float)(tx * 8) + 0.5f;
    const float bx1 = (float)(tx * 8 + 7) + 0.5f;
    const float by0 = (float)(ty * 8) + 0.5f;
    const float by1 = (float)(ty * 8 + 7) + 0.5f;

    // ---- Phase 1: per-lane cull test, ballot stream-compaction into LDS ----
    int count = 0;
    for (int base = 0; base < G_COUNT; base += 64) {
        int gi = base + lane;
        float4 p = pc[gi];            // coalesced
        float4 c = cc[gi];
        float2 orr = ow[gi];

        float ddx = fmaxf(fmaxf(bx0 - p.x, p.x - bx1), 0.0f);
        float ddy = fmaxf(fmaxf(by0 - p.y, p.y - by1), 0.0f);
        bool pass = (ddx * ddx + ddy * ddy) <= orr.y;

        unsigned long long m = __ballot(pass);
        int prefix = __builtin_amdgcn_mbcnt_hi((unsigned)(m >> 32),
                     __builtin_amdgcn_mbcnt_lo((unsigned)m, 0));
        if (pass) {
            int pos = count + prefix;
            s_pc[pos] = p;
            s_cc[pos] = c;
            s_op[pos] = orr.x;
        }
        count += __popcll(m);
    }
    __syncthreads();

    // ---- Phase 2: front-to-back compositing over survivors ----
    float T = 1.0f;
    float accr = 0.0f, accg = 0.0f, accb = 0.0f;

    for (int base = 0; base < count; base += 32) {
        int end = min(base + 32, count);
#pragma unroll 8
        for (int i = base; i < end; ++i) {
            float4 p = s_pc[i];   // uniform address -> broadcast
            float4 c = s_cc[i];
            float o = s_op[i];

            float dx = px - p.x;
            float dy = py - p.y;
            float sigma = 0.5f * (p.z * dx * dx + c.x * dy * dy) + p.w * dx * dy;
            float alpha = fminf(o * __expf(-sigma), ALPHA_MAX);
            bool zero = (sigma < 0.0f) || (alpha < ALPHA_THR);
            alpha = zero ? 0.0f : alpha;

            float om = 1.0f - alpha;
            float Tn = T * om;
            float w = (Tn >= T_THR) ? alpha * T : 0.0f;
            accr = fmaf(w, c.y, accr);
            accg = fmaf(w, c.z, accg);
            accb = fmaf(w, c.w, accb);
            T = Tn;
        }
        if (__ballot(T >= T_THR) == 0ULL) break;
    }

    float* o = out + ((size_t)pyi * IMG_W + pxi) * 3;
    o[0] = accr;
    o[1] = accg;
    o[2] = accb;
}

extern "C" void kernel_launch(void* const* d_in, const int* in_sizes, int n_in,
                              void* d_out, int out_size, void* d_ws, size_t ws_size,
                              hipStream_t stream) {
    const float* means2d = (const float*)d_in[0];
    const float* conics  = (const float*)d_in[1];
    const float* colors  = (const float*)d_in[2];
    const float* opac    = (const float*)d_in[3];
    const float* depths  = (const float*)d_in[4];
    float* out = (float*)d_out;

    char* ws = (char*)d_ws;
    float4* pc = (float4*)(ws);
    float4* cc = (float4*)(ws + 32768);
    float2* ow = (float2*)(ws + 65536);

    sort_gather_kernel<<<1, 1024, 0, stream>>>(means2d, conics, colors, opac, depths,
                                               pc, cc, ow);
    raster_kernel<<<256, 64, 0, stream>>>(pc, cc, ow, out);
}

// Round 3
// 46.890 us; speedup vs baseline: 7.7863x; 1.1968x over previous
//
#include <hip/hip_runtime.h>
#include <hip/hip_bf16.h>

#define G_COUNT 2048
#define IMG_W 128
#define IMG_H 128
#define ALPHA_THR (1.0f / 255.0f)
#define T_THR 1e-4f
#define ALPHA_MAX 0.99f
#define LOG2E 1.4426950408889634f

// ws layout (all float, 16B aligned):
//   [0)      float4 pc[2048] : {mx, my, A=0.5*a*log2e, C=0.5*c*log2e}   (32 KB)
//   [32768)  float4 cc[2048] : {B=b*log2e, col_r, col_g, col_b}         (32 KB)
//   [65536)  float2 ow[2048] : {opacity, l2o=log2(255*o)}               (16 KB)
//   [81920)  float  rr[2048] : cull radius^2                            ( 8 KB)

// ---------------- Kernel 1: rank-based stable depth sort + gather ----------------
// 32 blocks x 256 threads; 4 threads per gaussian, each counts 512 comparisons.
__global__ __launch_bounds__(256)
void sort_gather_kernel(const float* __restrict__ means2d,
                        const float* __restrict__ conics,
                        const float* __restrict__ colors,
                        const float* __restrict__ opac,
                        const float* __restrict__ depths,
                        float4* __restrict__ pc,
                        float4* __restrict__ cc,
                        float2* __restrict__ ow,
                        float* __restrict__ rr) {
    __shared__ unsigned long long keys[G_COUNT];
    const int t = threadIdx.x;

    // Stage all keys. Depths positive (0.1..10): raw bits preserve order.
    for (int i = t; i < G_COUNT; i += 256) {
        unsigned u = __float_as_uint(depths[i]);
        keys[i] = ((unsigned long long)u << 32) | (unsigned)i;  // unique, stable
    }
    __syncthreads();

    const int g = blockIdx.x * 64 + (t >> 2);   // my gaussian (original index)
    const int q = t & 3;                        // my quarter of the compare range
    const unsigned long long kme = keys[g];

    int cnt = 0;
    const int j0 = q * (G_COUNT / 4);
#pragma unroll 8
    for (int jj = 0; jj < G_COUNT / 4; ++jj) {
        cnt += (keys[j0 + jj] < kme) ? 1 : 0;
    }
    // Butterfly sum across the 4-thread group -> full rank.
    cnt += __shfl_xor(cnt, 1);
    cnt += __shfl_xor(cnt, 2);
    const int rank = cnt;

    if (q == 0) {
        float mx = means2d[2 * g + 0];
        float my = means2d[2 * g + 1];
        float a = conics[3 * g + 0];
        float c2 = conics[3 * g + 2];
        float o = opac[g];
        pc[rank] = make_float4(mx, my, 0.5f * a * LOG2E, 0.5f * c2 * LOG2E);
        ow[rank] = make_float2(o, __log2f(255.0f * o));
    } else if (q == 1) {
        float b = conics[3 * g + 1];
        float r = colors[3 * g + 0];
        float gg = colors[3 * g + 1];
        float bb = colors[3 * g + 2];
        cc[rank] = make_float4(b * LOG2E, r, gg, bb);
    } else if (q == 2) {
        float a = conics[3 * g + 0];
        float b = conics[3 * g + 1];
        float c2 = conics[3 * g + 2];
        float o = opac[g];
        // Conservative cull radius: sigma >= 0.5*lmin*|d|^2 -> alpha < 1/255
        // outside r2 = 2*ln(255*o)/lmin. 2% inflation for fp slop.
        float half_tr = 0.5f * (a + c2);
        float hd = 0.5f * (a - c2);
        float lmin = half_tr - sqrtf(hd * hd + b * b);
        float smax = logf(255.0f * o);   // o >= 0.05 -> positive
        rr[rank] = (lmin > 1e-12f) ? (2.04f * smax / lmin) : 1e30f;
    }
}

// ---------------- Kernel 2: chunked cull+compact into LDS, composite ----------------
// 256 blocks x 64 threads; block = one 8x8 pixel tile (1 wave).
#define CHUNK 1024
#define SUB 16

__global__ __launch_bounds__(64)
void raster_kernel(const float4* __restrict__ pc,
                   const float4* __restrict__ cc,
                   const float2* __restrict__ ow,
                   const float* __restrict__ rr,
                   float* __restrict__ out) {
    __shared__ float4 s_pc[CHUNK + SUB];
    __shared__ float4 s_cc[CHUNK + SUB];
    __shared__ float2 s_ow[CHUNK + SUB];

    const int tile = blockIdx.x;          // 16 x 16 tiles of 8x8 px
    const int tx = tile & 15;
    const int ty = tile >> 4;
    const int lane = threadIdx.x;
    const int pxi = tx * 8 + (lane & 7);
    const int pyi = ty * 8 + (lane >> 3);
    const float px = (float)pxi + 0.5f;
    const float py = (float)pyi + 0.5f;

    const float bx0 = (float)(tx * 8) + 0.5f;
    const float bx1 = (float)(tx * 8 + 7) + 0.5f;
    const float by0 = (float)(ty * 8) + 0.5f;
    const float by1 = (float)(ty * 8 + 7) + 0.5f;

    float T = 1.0f;
    float accr = 0.0f, accg = 0.0f, accb = 0.0f;
    bool alive = true;

    for (int cbase = 0; cbase < G_COUNT && alive; cbase += CHUNK) {
        // ---- cull + ballot stream-compaction into LDS (order-preserving) ----
        int cnt = 0;
        for (int k = 0; k < CHUNK; k += 64) {
            int gi = cbase + k + lane;
            float4 p = pc[gi];            // coalesced
            float4 c = cc[gi];
            float2 o2 = ow[gi];
            float r2 = rr[gi];

            float ddx = fmaxf(fmaxf(bx0 - p.x, p.x - bx1), 0.0f);
            float ddy = fmaxf(fmaxf(by0 - p.y, p.y - by1), 0.0f);
            bool pass = (ddx * ddx + ddy * ddy) <= r2;

            unsigned long long m = __ballot(pass);
            int prefix = __builtin_amdgcn_mbcnt_hi((unsigned)(m >> 32),
                         __builtin_amdgcn_mbcnt_lo((unsigned)m, 0));
            if (pass) {
                int pos = cnt + prefix;
                s_pc[pos] = p;
                s_cc[pos] = c;
                s_ow[pos] = o2;
            }
            cnt += __popcll(m);
        }
        // Pad to a multiple of SUB with zero-contribution dummies.
        int padded = (cnt + SUB - 1) & ~(SUB - 1);
        for (int i = cnt + lane; i < padded; i += 64) {
            s_pc[i] = make_float4(0.f, 0.f, 0.f, 0.f);
            s_cc[i] = make_float4(0.f, 0.f, 0.f, 0.f);
            s_ow[i] = make_float2(0.f, -1.f);   // l2o=-1 -> s2(=0) > l2o -> zeroed
        }
        __syncthreads();

        // ---- front-to-back compositing; fixed SUB-trip inner loop, full unroll ----
        for (int base = 0; base < padded; base += SUB) {
#pragma unroll
            for (int j = 0; j < SUB; ++j) {
                float4 p = s_pc[base + j];   // uniform address -> broadcast
                float4 c = s_cc[base + j];
                float2 o2 = s_ow[base + j];

                float dx = px - p.x;
                float dy = py - p.y;
                // s2 = sigma * log2(e); conic pre-scaled in sort kernel.
                float s2 = fmaf(p.z * dx, dx, fmaf(p.w * dy, dy, (c.x * dx) * dy));
#if __has_builtin(__builtin_amdgcn_exp2f)
                float e = __builtin_amdgcn_exp2f(-s2);
#else
                float e = __expf(-s2 * 0.6931471805599453f);
#endif
                float al = fminf(o2.x * e, ALPHA_MAX);
                al = (s2 < 0.0f || s2 > o2.y) ? 0.0f : al;

                float om = 1.0f - al;
                float Tn = T * om;
                float w = (Tn >= T_THR) ? al * T : 0.0f;
                accr = fmaf(w, c.y, accr);
                accg = fmaf(w, c.z, accg);
                accb = fmaf(w, c.w, accb);
                T = Tn;
            }
            if (__ballot(T >= T_THR) == 0ULL) { alive = false; break; }
        }
        __syncthreads();
    }

    float* o = out + ((size_t)pyi * IMG_W + pxi) * 3;
    o[0] = accr;
    o[1] = accg;
    o[2] = accb;
}

extern "C" void kernel_launch(void* const* d_in, const int* in_sizes, int n_in,
                              void* d_out, int out_size, void* d_ws, size_t ws_size,
                              hipStream_t stream) {
    const float* means2d = (const float*)d_in[0];
    const float* conics  = (const float*)d_in[1];
    const float* colors  = (const float*)d_in[2];
    const float* opac    = (const float*)d_in[3];
    const float* depths  = (const float*)d_in[4];
    float* out = (float*)d_out;

    char* ws = (char*)d_ws;
    float4* pc = (float4*)(ws);
    float4* cc = (float4*)(ws + 32768);
    float2* ow = (float2*)(ws + 65536);
    float*  rr = (float*)(ws + 81920);

    sort_gather_kernel<<<32, 256, 0, stream>>>(means2d, conics, colors, opac, depths,
                                               pc, cc, ow, rr);
    raster_kernel<<<256, 64, 0, stream>>>(pc, cc, ow, rr, out);
}

// Round 4
// 33.464 us; speedup vs baseline: 10.9103x; 1.4012x over previous
//
#include <hip/hip_runtime.h>
#include <hip/hip_bf16.h>

#define G_COUNT 2048
#define IMG_W 128
#define IMG_H 128
#define ALPHA_THR (1.0f / 255.0f)
#define T_THR 1e-4f
#define ALPHA_MAX 0.99f
#define LOG2E 1.4426950408889634f

// ws layout (16B aligned):
//   [0)      float4 pc[2048] : {mx, my, A=0.5*a*log2e, C=0.5*c*log2e}   (32 KB)
//   [32768)  float4 cc[2048] : {B=b*log2e, col_r, col_g, col_b}         (32 KB)
//   [65536)  float2 ow[2048] : {opacity, l2o=log2(255*o)}               (16 KB)
//   [81920)  float  rr[2048] : cull radius^2                            ( 8 KB)

// ---------------- Kernel 1: rank-based stable depth sort + gather ----------------
__global__ __launch_bounds__(256)
void sort_gather_kernel(const float* __restrict__ means2d,
                        const float* __restrict__ conics,
                        const float* __restrict__ colors,
                        const float* __restrict__ opac,
                        const float* __restrict__ depths,
                        float4* __restrict__ pc,
                        float4* __restrict__ cc,
                        float2* __restrict__ ow,
                        float* __restrict__ rr) {
    __shared__ unsigned long long keys[G_COUNT];
    const int t = threadIdx.x;

    for (int i = t; i < G_COUNT; i += 256) {
        unsigned u = __float_as_uint(depths[i]);   // depths > 0: bits preserve order
        keys[i] = ((unsigned long long)u << 32) | (unsigned)i;  // unique, stable
    }
    __syncthreads();

    const int g = blockIdx.x * 64 + (t >> 2);
    const int q = t & 3;
    const unsigned long long kme = keys[g];

    int cnt = 0;
    const int j0 = q * (G_COUNT / 4);
#pragma unroll 8
    for (int jj = 0; jj < G_COUNT / 4; ++jj) {
        cnt += (keys[j0 + jj] < kme) ? 1 : 0;
    }
    cnt += __shfl_xor(cnt, 1);
    cnt += __shfl_xor(cnt, 2);
    const int rank = cnt;

    if (q == 0) {
        float mx = means2d[2 * g + 0];
        float my = means2d[2 * g + 1];
        float a = conics[3 * g + 0];
        float c2 = conics[3 * g + 2];
        float o = opac[g];
        pc[rank] = make_float4(mx, my, 0.5f * a * LOG2E, 0.5f * c2 * LOG2E);
        ow[rank] = make_float2(o, __log2f(255.0f * o));
    } else if (q == 1) {
        float b = conics[3 * g + 1];
        float r = colors[3 * g + 0];
        float gg = colors[3 * g + 1];
        float bb = colors[3 * g + 2];
        cc[rank] = make_float4(b * LOG2E, r, gg, bb);
    } else if (q == 2) {
        float a = conics[3 * g + 0];
        float b = conics[3 * g + 1];
        float c2 = conics[3 * g + 2];
        float o = opac[g];
        float half_tr = 0.5f * (a + c2);
        float hd = 0.5f * (a - c2);
        float lmin = half_tr - sqrtf(hd * hd + b * b);
        float smax = logf(255.0f * o);
        rr[rank] = (lmin > 1e-12f) ? (2.04f * smax / lmin) : 1e30f;
    }
}

// ---------------- Kernel 2: 4-wave tile raster, quad-slot composite ----------------
// 256 blocks x 256 threads; block = one 8x8 tile. Wave w culls depth segment w
// into LDS region w; composite processes regions 0..3 in order (global depth
// order preserved), 4 gaussians per iteration via lane-quad slots.
#define SEG 512
#define SEGP 516   // region stride: capacity 512 + room for <=3 pad dummies

__global__ __launch_bounds__(256)
void raster_kernel(const float4* __restrict__ pc,
                   const float4* __restrict__ cc,
                   const float2* __restrict__ ow,
                   const float* __restrict__ rr,
                   float* __restrict__ out) {
    __shared__ float4 s_pc[4 * SEGP];
    __shared__ float4 s_cc[4 * SEGP];
    __shared__ float2 s_ow[4 * SEGP];
    __shared__ int s_cnt[4];

    const int tile = blockIdx.x;          // 16 x 16 tiles of 8x8 px
    const int tx = tile & 15;
    const int ty = tile >> 4;
    const int tid = threadIdx.x;
    const int wave = tid >> 6;            // 0..3
    const int lane = tid & 63;
    const int slot = lane & 3;            // gaussian slot within quad
    const int p = wave * 16 + (lane >> 2);  // pixel 0..63 of the tile
    const int pxi = tx * 8 + (p & 7);
    const int pyi = ty * 8 + (p >> 3);
    const float px = (float)pxi + 0.5f;
    const float py = (float)pyi + 0.5f;

    const float bx0 = (float)(tx * 8) + 0.5f;
    const float bx1 = (float)(tx * 8 + 7) + 0.5f;
    const float by0 = (float)(ty * 8) + 0.5f;
    const float by1 = (float)(ty * 8 + 7) + 0.5f;

    // ---- Phase 1: wave w compacts depth segment w into LDS region w ----
    int cnt = 0;
    const int gseg = wave * SEG;
    for (int k = 0; k < SEG; k += 64) {
        int gi = gseg + k + lane;
        float4 pp = pc[gi];               // coalesced
        float4 c = cc[gi];
        float2 o2 = ow[gi];
        float r2 = rr[gi];

        float ddx = fmaxf(fmaxf(bx0 - pp.x, pp.x - bx1), 0.0f);
        float ddy = fmaxf(fmaxf(by0 - pp.y, pp.y - by1), 0.0f);
        bool pass = (ddx * ddx + ddy * ddy) <= r2;

        unsigned long long m = __ballot(pass);
        int prefix = __builtin_amdgcn_mbcnt_hi((unsigned)(m >> 32),
                     __builtin_amdgcn_mbcnt_lo((unsigned)m, 0));
        if (pass) {
            int pos = wave * SEGP + cnt + prefix;
            s_pc[pos] = pp;
            s_cc[pos] = c;
            s_ow[pos] = o2;
        }
        cnt += __popcll(m);
    }
    // Pad region to a multiple of 4 with zero-contribution dummies.
    int padded = (cnt + 3) & ~3;
    if (lane < padded - cnt) {
        int pos = wave * SEGP + cnt + lane;
        s_pc[pos] = make_float4(0.f, 0.f, 0.f, 0.f);
        s_cc[pos] = make_float4(0.f, 0.f, 0.f, 0.f);
        s_ow[pos] = make_float2(0.f, -1.f);   // s2(=0) > l2o(-1) -> alpha forced 0
    }
    if (lane == 0) s_cnt[wave] = padded;
    __syncthreads();

    // ---- Phase 2: composite regions 0..3 in depth order, 4 gaussians/iter ----
    float T = 1.0f;
    float accr = 0.0f, accg = 0.0f, accb = 0.0f;
    bool alive = true;

    for (int r = 0; r < 4 && alive; ++r) {
        const int n = s_cnt[r];
        const int roff = r * SEGP;
        for (int base = 0; base < n; base += 4) {
            int idx = roff + base + slot;
            float4 pp = s_pc[idx];        // 4 distinct addrs/quad, disjoint banks
            float4 c = s_cc[idx];
            float2 o2 = s_ow[idx];

            float dx = px - pp.x;
            float dy = py - pp.y;
            float s2 = fmaf(pp.z * dx, dx, fmaf(pp.w * dy, dy, (c.x * dx) * dy));
#if __has_builtin(__builtin_amdgcn_exp2f)
            float e = __builtin_amdgcn_exp2f(-s2);
#else
            float e = __expf(-s2 * 0.6931471805599453f);
#endif
            float al = fminf(o2.x * e, ALPHA_MAX);
            al = (s2 < 0.0f || s2 > o2.y) ? 0.0f : al;
            float om = 1.0f - al;

            // Quad prefix products of om -> per-slot T_before.
            float x1 = __shfl_xor(om, 1);     // neighbor's om
            float p2 = om * x1;               // pair product
            float x2 = __shfl_xor(p2, 2);     // other pair's product
            float qp = p2 * x2;               // quad product (bit-uniform in quad)
            float pre = (slot & 1) ? x1 : 1.0f;
            if (slot & 2) pre *= x2;          // slot prefix: 1, o0, o0o1, o0o1o2

            float Tb = T * pre;
            float Tn = Tb * om;
            float w = (Tn >= T_THR) ? al * Tb : 0.0f;
            accr = fmaf(w, c.y, accr);
            accg = fmaf(w, c.z, accg);
            accb = fmaf(w, c.w, accb);
            T *= qp;

            if (__ballot(T >= T_THR) == 0ULL) { alive = false; break; }
        }
    }

    // Quad-reduce rgb; lanes 0..2 of each quad store channels r,g,b.
    float sr = accr + __shfl_xor(accr, 1); sr += __shfl_xor(sr, 2);
    float sg = accg + __shfl_xor(accg, 1); sg += __shfl_xor(sg, 2);
    float sb = accb + __shfl_xor(accb, 1); sb += __shfl_xor(sb, 2);
    if (slot < 3) {
        float v = (slot == 0) ? sr : ((slot == 1) ? sg : sb);
        out[((size_t)pyi * IMG_W + pxi) * 3 + slot] = v;
    }
}

extern "C" void kernel_launch(void* const* d_in, const int* in_sizes, int n_in,
                              void* d_out, int out_size, void* d_ws, size_t ws_size,
                              hipStream_t stream) {
    const float* means2d = (const float*)d_in[0];
    const float* conics  = (const float*)d_in[1];
    const float* colors  = (const float*)d_in[2];
    const float* opac    = (const float*)d_in[3];
    const float* depths  = (const float*)d_in[4];
    float* out = (float*)d_out;

    char* ws = (char*)d_ws;
    float4* pc = (float4*)(ws);
    float4* cc = (float4*)(ws + 32768);
    float2* ow = (float2*)(ws + 65536);
    float*  rr = (float*)(ws + 81920);

    sort_gather_kernel<<<32, 256, 0, stream>>>(means2d, conics, colors, opac, depths,
                                               pc, cc, ow, rr);
    raster_kernel<<<256, 256, 0, stream>>>(pc, cc, ow, rr, out);
}

// Round 5
// 29.443 us; speedup vs baseline: 12.4004x; 1.1366x over previous
//
#include <hip/hip_runtime.h>
#include <hip/hip_bf16.h>

#define G_COUNT 2048
#define IMG_W 128
#define IMG_H 128
#define ALPHA_THR (1.0f / 255.0f)
#define T_THR 1e-4f
#define ALPHA_MAX 0.99f
#define LOG2E 1.4426950408889634f

// ws layout (16B aligned):
//   [0)      float4 pc[2048] : {mx, my, A=0.5*a*log2e, C=0.5*c*log2e}   (32 KB)
//   [32768)  float4 cc[2048] : {B=b*log2e, col_r, col_g, col_b}         (32 KB)
//   [65536)  float2 ow[2048] : {opacity, l2o=log2(255*o)}               (16 KB)
//   [81920)  float  rr[2048] : cull radius^2                            ( 8 KB)

// ---------------- Kernel 1: rank-based stable depth sort + gather ----------------
// 64 blocks x 256 threads; 8 threads per gaussian, each counts 256 comparisons.
__global__ __launch_bounds__(256)
void sort_gather_kernel(const float* __restrict__ means2d,
                        const float* __restrict__ conics,
                        const float* __restrict__ colors,
                        const float* __restrict__ opac,
                        const float* __restrict__ depths,
                        float4* __restrict__ pc,
                        float4* __restrict__ cc,
                        float2* __restrict__ ow,
                        float* __restrict__ rr) {
    __shared__ unsigned long long keys[G_COUNT];
    const int t = threadIdx.x;

    for (int i = t; i < G_COUNT; i += 256) {
        unsigned u = __float_as_uint(depths[i]);   // depths > 0: bits preserve order
        keys[i] = ((unsigned long long)u << 32) | (unsigned)i;  // unique, stable
    }
    __syncthreads();

    const int g = blockIdx.x * 32 + (t >> 3);   // my gaussian (original index)
    const int q = t & 7;                        // my eighth of the compare range
    const unsigned long long kme = keys[g];

    int cnt = 0;
    const int j0 = q * (G_COUNT / 8);
#pragma unroll 8
    for (int jj = 0; jj < G_COUNT / 8; ++jj) {
        cnt += (keys[j0 + jj] < kme) ? 1 : 0;
    }
    cnt += __shfl_xor(cnt, 1);
    cnt += __shfl_xor(cnt, 2);
    cnt += __shfl_xor(cnt, 4);
    const int rank = cnt;

    if (q == 0) {
        float mx = means2d[2 * g + 0];
        float my = means2d[2 * g + 1];
        float a = conics[3 * g + 0];
        float c2 = conics[3 * g + 2];
        float o = opac[g];
        pc[rank] = make_float4(mx, my, 0.5f * a * LOG2E, 0.5f * c2 * LOG2E);
        ow[rank] = make_float2(o, __log2f(255.0f * o));
    } else if (q == 1) {
        float b = conics[3 * g + 1];
        float r = colors[3 * g + 0];
        float gg = colors[3 * g + 1];
        float bb = colors[3 * g + 2];
        cc[rank] = make_float4(b * LOG2E, r, gg, bb);
    } else if (q == 2) {
        float a = conics[3 * g + 0];
        float b = conics[3 * g + 1];
        float c2 = conics[3 * g + 2];
        float o = opac[g];
        // Conservative cull radius: sigma >= 0.5*lmin*|d|^2 -> alpha < 1/255
        // outside r2 = 2*ln(255*o)/lmin. 2% inflation for fp slop.
        float half_tr = 0.5f * (a + c2);
        float hd = 0.5f * (a - c2);
        float lmin = half_tr - sqrtf(hd * hd + b * b);
        float smax = logf(255.0f * o);
        rr[rank] = (lmin > 1e-12f) ? (2.04f * smax / lmin) : 1e30f;
    }
}

// ---------------- Kernel 2: 4-wave tile raster, quad-slot composite ----------------
// 256 blocks x 256 threads; block = one 8x8 tile. Wave w culls depth segment w
// into LDS region w (regions 0..3 = global depth order). Composite processes
// 32 gaussians per group (8 quad-iterations, fully unrolled, no internal
// break) so ds_reads/exp/shfls of all 8 iterations pipeline; only the short
// T-chain is serial. Ballot early-exit once per group.
#define SEG 512
#define SEGP 544   // region stride: capacity 512 + up to 31 pad dummies

__global__ __launch_bounds__(256)
void raster_kernel(const float4* __restrict__ pc,
                   const float4* __restrict__ cc,
                   const float2* __restrict__ ow,
                   const float* __restrict__ rr,
                   float* __restrict__ out) {
    __shared__ float4 s_pc[4 * SEGP];
    __shared__ float4 s_cc[4 * SEGP];
    __shared__ float2 s_ow[4 * SEGP];
    __shared__ int s_cnt[4];

    const int tile = blockIdx.x;          // 16 x 16 tiles of 8x8 px
    const int tx = tile & 15;
    const int ty = tile >> 4;
    const int tid = threadIdx.x;
    const int wave = tid >> 6;            // 0..3
    const int lane = tid & 63;
    const int slot = lane & 3;            // gaussian slot within quad
    const int p = wave * 16 + (lane >> 2);  // pixel 0..63 of the tile
    const int pxi = tx * 8 + (p & 7);
    const int pyi = ty * 8 + (p >> 3);
    const float px = (float)pxi + 0.5f;
    const float py = (float)pyi + 0.5f;

    const float bx0 = (float)(tx * 8) + 0.5f;
    const float bx1 = (float)(tx * 8 + 7) + 0.5f;
    const float by0 = (float)(ty * 8) + 0.5f;
    const float by1 = (float)(ty * 8 + 7) + 0.5f;

    // ---- Phase 1: wave w compacts depth segment w into LDS region w ----
    int cnt = 0;
    const int gseg = wave * SEG;
    for (int k = 0; k < SEG; k += 64) {
        int gi = gseg + k + lane;
        float4 pp = pc[gi];               // coalesced
        float4 c = cc[gi];
        float2 o2 = ow[gi];
        float r2 = rr[gi];

        float ddx = fmaxf(fmaxf(bx0 - pp.x, pp.x - bx1), 0.0f);
        float ddy = fmaxf(fmaxf(by0 - pp.y, pp.y - by1), 0.0f);
        bool pass = (ddx * ddx + ddy * ddy) <= r2;

        unsigned long long m = __ballot(pass);
        int prefix = __builtin_amdgcn_mbcnt_hi((unsigned)(m >> 32),
                     __builtin_amdgcn_mbcnt_lo((unsigned)m, 0));
        if (pass) {
            int pos = wave * SEGP + cnt + prefix;
            s_pc[pos] = pp;
            s_cc[pos] = c;
            s_ow[pos] = o2;
        }
        cnt += __popcll(m);
    }
    // Pad region to a multiple of 32 with zero-contribution dummies.
    int padded = (cnt + 31) & ~31;
    if (lane < padded - cnt) {
        int pos = wave * SEGP + cnt + lane;
        s_pc[pos] = make_float4(0.f, 0.f, 0.f, 0.f);
        s_cc[pos] = make_float4(0.f, 0.f, 0.f, 0.f);
        s_ow[pos] = make_float2(0.f, -1.f);   // s2(=0) > l2o(-1) -> alpha forced 0
    }
    if (lane == 0) s_cnt[wave] = padded;
    __syncthreads();

    // ---- Phase 2: composite regions 0..3 in depth order ----
    float T = 1.0f;
    float accr = 0.0f, accg = 0.0f, accb = 0.0f;
    bool alive = true;

    for (int r = 0; r < 4 && alive; ++r) {
        const int n = s_cnt[r];
        const int roff = r * SEGP;
        for (int base = 0; base < n && alive; base += 32) {
#pragma unroll
            for (int jj = 0; jj < 8; ++jj) {
                int idx = roff + base + jj * 4 + slot;
                float4 pp = s_pc[idx];    // 4 distinct addrs/wave, 16-lane bcast
                float4 c = s_cc[idx];
                float2 o2 = s_ow[idx];

                float dx = px - pp.x;
                float dy = py - pp.y;
                float s2 = fmaf(pp.z * dx, dx, fmaf(pp.w * dy, dy, (c.x * dx) * dy));
#if __has_builtin(__builtin_amdgcn_exp2f)
                float e = __builtin_amdgcn_exp2f(-s2);
#else
                float e = __expf(-s2 * 0.6931471805599453f);
#endif
                float al = fminf(o2.x * e, ALPHA_MAX);
                al = (s2 < 0.0f || s2 > o2.y) ? 0.0f : al;
                float om = 1.0f - al;

                // Quad prefix products of om -> per-slot T_before (T-independent).
                float x1 = __shfl_xor(om, 1);
                float p2 = om * x1;
                float x2 = __shfl_xor(p2, 2);
                float qp = p2 * x2;               // quad product (bit-uniform)
                float pre = (slot & 1) ? x1 : 1.0f;
                if (slot & 2) pre *= x2;          // prefix: 1, o0, o0o1, o0o1o2

                float Tb = T * pre;               // short serial T-chain
                float Tn = Tb * om;
                float w = (Tn >= T_THR) ? al * Tb : 0.0f;
                accr = fmaf(w, c.y, accr);
                accg = fmaf(w, c.z, accg);
                accb = fmaf(w, c.w, accb);
                T *= qp;
            }
            if (__ballot(T >= T_THR) == 0ULL) alive = false;
        }
    }

    // Quad-reduce rgb; lanes 0..2 of each quad store channels r,g,b.
    float sr = accr + __shfl_xor(accr, 1); sr += __shfl_xor(sr, 2);
    float sg = accg + __shfl_xor(accg, 1); sg += __shfl_xor(sg, 2);
    float sb = accb + __shfl_xor(accb, 1); sb += __shfl_xor(sb, 2);
    if (slot < 3) {
        float v = (slot == 0) ? sr : ((slot == 1) ? sg : sb);
        out[((size_t)pyi * IMG_W + pxi) * 3 + slot] = v;
    }
}

extern "C" void kernel_launch(void* const* d_in, const int* in_sizes, int n_in,
                              void* d_out, int out_size, void* d_ws, size_t ws_size,
                              hipStream_t stream) {
    const float* means2d = (const float*)d_in[0];
    const float* conics  = (const float*)d_in[1];
    const float* colors  = (const float*)d_in[2];
    const float* opac    = (const float*)d_in[3];
    const float* depths  = (const float*)d_in[4];
    float* out = (float*)d_out;

    char* ws = (char*)d_ws;
    float4* pc = (float4*)(ws);
    float4* cc = (float4*)(ws + 32768);
    float2* ow = (float2*)(ws + 65536);
    float*  rr = (float*)(ws + 81920);

    sort_gather_kernel<<<64, 256, 0, stream>>>(means2d, conics, colors, opac, depths,
                                               pc, cc, ow, rr);
    raster_kernel<<<256, 256, 0, stream>>>(pc, cc, ow, rr, out);
}

// Round 6
// 24.603 us; speedup vs baseline: 14.8399x; 1.1967x over previous
//
#include <hip/hip_runtime.h>
#include <hip/hip_bf16.h>

#define G_COUNT 2048
#define IMG_W 128
#define IMG_H 128
#define ALPHA_THR (1.0f / 255.0f)
#define T_THR 1e-4f
#define ALPHA_MAX 0.99f
#define LOG2E 1.4426950408889634f

// DPP quad_perm: xor1 = [1,0,3,2] = 0xB1, xor2 = [2,3,0,1] = 0x4E.
template <int CTRL>
__device__ __forceinline__ float qperm(float x) {
    int i = __float_as_int(x);
    int r = __builtin_amdgcn_update_dpp(i, i, CTRL, 0xF, 0xF, false);
    return __int_as_float(r);
}

// ws layout (16B aligned):
//   [0)      float4 pc[2048] : {mx, my, A=0.5*a*log2e, C=0.5*c*log2e}   (32 KB)
//   [32768)  float4 cc[2048] : {B=b*log2e, col_r, col_g, col_b}         (32 KB)
//   [65536)  float2 ow[2048] : {opacity, l2o=log2(255*o)}               (16 KB)
//   [81920)  float  rr[2048] : cull radius^2                            ( 8 KB)

// ---------------- Kernel 1: rank-based stable depth sort + gather ----------------
// 64 blocks x 256 threads; 8 threads per gaussian, each counts 256 comparisons.
// Interleaved j-partition (keys[jj*8+q]) -> 8 distinct addresses per wave
// spread over 16 banks, conflict-free (old q*256+jj layout was same-bank).
__global__ __launch_bounds__(256)
void sort_gather_kernel(const float* __restrict__ means2d,
                        const float* __restrict__ conics,
                        const float* __restrict__ colors,
                        const float* __restrict__ opac,
                        const float* __restrict__ depths,
                        float4* __restrict__ pc,
                        float4* __restrict__ cc,
                        float2* __restrict__ ow,
                        float* __restrict__ rr) {
    __shared__ unsigned long long keys[G_COUNT];
    const int t = threadIdx.x;

    for (int i = t; i < G_COUNT; i += 256) {
        unsigned u = __float_as_uint(depths[i]);   // depths > 0: bits preserve order
        keys[i] = ((unsigned long long)u << 32) | (unsigned)i;  // unique, stable
    }
    __syncthreads();

    const int g = blockIdx.x * 32 + (t >> 3);   // my gaussian (original index)
    const int q = t & 7;                        // my residue class of j
    const unsigned long long kme = keys[g];

    int cnt = 0;
#pragma unroll 8
    for (int jj = 0; jj < G_COUNT / 8; ++jj) {
        cnt += (keys[jj * 8 + q] < kme) ? 1 : 0;
    }
    cnt += __shfl_xor(cnt, 1);
    cnt += __shfl_xor(cnt, 2);
    cnt += __shfl_xor(cnt, 4);
    const int rank = cnt;

    if (q == 0) {
        float mx = means2d[2 * g + 0];
        float my = means2d[2 * g + 1];
        float a = conics[3 * g + 0];
        float c2 = conics[3 * g + 2];
        float o = opac[g];
        pc[rank] = make_float4(mx, my, 0.5f * a * LOG2E, 0.5f * c2 * LOG2E);
        ow[rank] = make_float2(o, __log2f(255.0f * o));
    } else if (q == 1) {
        float b = conics[3 * g + 1];
        float r = colors[3 * g + 0];
        float gg = colors[3 * g + 1];
        float bb = colors[3 * g + 2];
        cc[rank] = make_float4(b * LOG2E, r, gg, bb);
    } else if (q == 2) {
        float a = conics[3 * g + 0];
        float b = conics[3 * g + 1];
        float c2 = conics[3 * g + 2];
        float o = opac[g];
        // Conservative cull radius: sigma >= 0.5*lmin*|d|^2 -> alpha < 1/255
        // outside r2 = 2*ln(255*o)/lmin. 2% inflation for fp slop.
        float half_tr = 0.5f * (a + c2);
        float hd = 0.5f * (a - c2);
        float lmin = half_tr - sqrtf(hd * hd + b * b);
        float smax = logf(255.0f * o);
        rr[rank] = (lmin > 1e-12f) ? (2.04f * smax / lmin) : 1e30f;
    }
}

// ---------------- Kernel 2: 4-wave tile raster, quad-slot composite ----------------
// 256 blocks x 256 threads; block = one 8x8 tile. Wave w culls depth segment w
// into LDS region w (regions 0..3 = global depth order). Composite: 32
// gaussians per group; group body = {stage 24 ds_reads to regs} then
// {8 unrolled quad-iterations with DPP prefix products}. Ballot exit per group.
#define SEG 512
#define SEGP 544   // region stride: capacity 512 + up to 31 pad dummies

__global__ __launch_bounds__(256)
void raster_kernel(const float4* __restrict__ pc,
                   const float4* __restrict__ cc,
                   const float2* __restrict__ ow,
                   const float* __restrict__ rr,
                   float* __restrict__ out) {
    __shared__ float4 s_pc[4 * SEGP];
    __shared__ float4 s_cc[4 * SEGP];
    __shared__ float2 s_ow[4 * SEGP];
    __shared__ int s_cnt[4];

    const int tile = blockIdx.x;          // 16 x 16 tiles of 8x8 px
    const int tx = tile & 15;
    const int ty = tile >> 4;
    const int tid = threadIdx.x;
    const int wave = tid >> 6;            // 0..3
    const int lane = tid & 63;
    const int slot = lane & 3;            // gaussian slot within quad
    const int p = wave * 16 + (lane >> 2);  // pixel 0..63 of the tile
    const int pxi = tx * 8 + (p & 7);
    const int pyi = ty * 8 + (p >> 3);
    const float px = (float)pxi + 0.5f;
    const float py = (float)pyi + 0.5f;

    const float bx0 = (float)(tx * 8) + 0.5f;
    const float bx1 = (float)(tx * 8 + 7) + 0.5f;
    const float by0 = (float)(ty * 8) + 0.5f;
    const float by1 = (float)(ty * 8 + 7) + 0.5f;

    // ---- Phase 1: wave w compacts depth segment w into LDS region w ----
    int cnt = 0;
    const int gseg = wave * SEG;
    for (int k = 0; k < SEG; k += 64) {
        int gi = gseg + k + lane;
        float4 pp = pc[gi];               // coalesced
        float4 c = cc[gi];
        float2 o2 = ow[gi];
        float r2 = rr[gi];

        float ddx = fmaxf(fmaxf(bx0 - pp.x, pp.x - bx1), 0.0f);
        float ddy = fmaxf(fmaxf(by0 - pp.y, pp.y - by1), 0.0f);
        bool pass = (ddx * ddx + ddy * ddy) <= r2;

        unsigned long long m = __ballot(pass);
        int prefix = __builtin_amdgcn_mbcnt_hi((unsigned)(m >> 32),
                     __builtin_amdgcn_mbcnt_lo((unsigned)m, 0));
        if (pass) {
            int pos = wave * SEGP + cnt + prefix;
            s_pc[pos] = pp;
            s_cc[pos] = c;
            s_ow[pos] = o2;
        }
        cnt += __popcll(m);
    }
    // Pad region to a multiple of 32 with zero-contribution dummies.
    int padded = (cnt + 31) & ~31;
    if (lane < padded - cnt) {
        int pos = wave * SEGP + cnt + lane;
        s_pc[pos] = make_float4(0.f, 0.f, 0.f, 0.f);
        s_cc[pos] = make_float4(0.f, 0.f, 0.f, 0.f);
        s_ow[pos] = make_float2(0.f, -1.f);   // s2(=0) > l2o(-1) -> alpha forced 0
    }
    if (lane == 0) s_cnt[wave] = padded;
    __syncthreads();

    // ---- Phase 2: composite regions 0..3 in depth order ----
    float T = 1.0f;
    float accr = 0.0f, accg = 0.0f, accb = 0.0f;
    bool alive = true;

    for (int r = 0; r < 4 && alive; ++r) {
        const int n = s_cnt[r];
        const int roff = r * SEGP;
        for (int base = 0; base < n && alive; base += 32) {
            // Stage the whole group to registers first: 24 ds_reads issue
            // back-to-back, one lgkmcnt wait amortized over the group.
            float4 lp[8], lc[8];
            float2 lo[8];
#pragma unroll
            for (int jj = 0; jj < 8; ++jj) {
                int idx = roff + base + jj * 4 + slot;
                lp[jj] = s_pc[idx];
                lc[jj] = s_cc[idx];
                lo[jj] = s_ow[idx];
            }
#pragma unroll
            for (int jj = 0; jj < 8; ++jj) {
                float4 pp = lp[jj];
                float4 c = lc[jj];
                float2 o2 = lo[jj];

                float dx = px - pp.x;
                float dy = py - pp.y;
                float s2 = fmaf(pp.z * dx, dx, fmaf(pp.w * dy, dy, (c.x * dx) * dy));
#if __has_builtin(__builtin_amdgcn_exp2f)
                float e = __builtin_amdgcn_exp2f(-s2);
#else
                float e = __expf(-s2 * 0.6931471805599453f);
#endif
                float al = fminf(o2.x * e, ALPHA_MAX);
                al = (s2 < 0.0f || s2 > o2.y) ? 0.0f : al;
                float om = 1.0f - al;

                // Quad prefix products via DPP (VALU, ~4 cyc — not LDS).
                float x1 = qperm<0xB1>(om);       // xor 1
                float p2 = om * x1;
                float x2 = qperm<0x4E>(p2);       // xor 2
                float qp = p2 * x2;               // quad product (bit-uniform)
                float pre = (slot & 1) ? x1 : 1.0f;
                if (slot & 2) pre *= x2;          // prefix: 1, o0, o0o1, o0o1o2

                float Tb = T * pre;               // short serial T-chain
                float Tn = Tb * om;
                float w = (Tn >= T_THR) ? al * Tb : 0.0f;
                accr = fmaf(w, c.y, accr);
                accg = fmaf(w, c.z, accg);
                accb = fmaf(w, c.w, accb);
                T *= qp;
            }
            if (__ballot(T >= T_THR) == 0ULL) alive = false;
        }
    }

    // Quad-reduce rgb via DPP; lanes 0..2 of each quad store channels r,g,b.
    float sr = accr + qperm<0xB1>(accr); sr += qperm<0x4E>(sr);
    float sg = accg + qperm<0xB1>(accg); sg += qperm<0x4E>(sg);
    float sb = accb + qperm<0xB1>(accb); sb += qperm<0x4E>(sb);
    if (slot < 3) {
        float v = (slot == 0) ? sr : ((slot == 1) ? sg : sb);
        out[((size_t)pyi * IMG_W + pxi) * 3 + slot] = v;
    }
}

extern "C" void kernel_launch(void* const* d_in, const int* in_sizes, int n_in,
                              void* d_out, int out_size, void* d_ws, size_t ws_size,
                              hipStream_t stream) {
    const float* means2d = (const float*)d_in[0];
    const float* conics  = (const float*)d_in[1];
    const float* colors  = (const float*)d_in[2];
    const float* opac    = (const float*)d_in[3];
    const float* depths  = (const float*)d_in[4];
    float* out = (float*)d_out;

    char* ws = (char*)d_ws;
    float4* pc = (float4*)(ws);
    float4* cc = (float4*)(ws + 32768);
    float2* ow = (float2*)(ws + 65536);
    float*  rr = (float*)(ws + 81920);

    sort_gather_kernel<<<64, 256, 0, stream>>>(means2d, conics, colors, opac, depths,
                                               pc, cc, ow, rr);
    raster_kernel<<<256, 256, 0, stream>>>(pc, cc, ow, rr, out);
}

// Round 7
// 20.336 us; speedup vs baseline: 17.9535x; 1.2098x over previous
//
#include <hip/hip_runtime.h>
#include <hip/hip_bf16.h>

#define G_COUNT 2048
#define IMG_W 128
#define IMG_H 128
#define T_THR 1e-4f
#define ALPHA_MAX 0.99f
#define LOG2E 1.4426950408889634f
#define LN2 0.6931471805599453f

// DPP quad_perm: xor1 = [1,0,3,2] = 0xB1, xor2 = [2,3,0,1] = 0x4E.
template <int CTRL>
__device__ __forceinline__ float qperm(float x) {
    int i = __float_as_int(x);
    int r = __builtin_amdgcn_update_dpp(i, i, CTRL, 0xF, 0xF, false);
    return __int_as_float(r);
}

// Single fused kernel: 256 blocks x 256 threads, one 8x8-pixel tile per block.
// Phase 1: cull all 2048 gaussians from raw inputs (L2-resident, 256x reuse),
//          wave-aggregated atomic compaction of processed records into LDS.
// Phase 2: per-tile stable rank sort of survivors by (depth_bits, idx) unique
//          key -> permutation array (order-independent of compaction order,
//          so the atomicAdd nondeterminism does not reach the output).
// Phase 3: quad-slot DPP composite (4 gaussians/iter, 32/group), as round 6.
__global__ __launch_bounds__(256)
void raster_fused(const float* __restrict__ means2d,
                  const float* __restrict__ conics,
                  const float* __restrict__ colors,
                  const float* __restrict__ opac,
                  const float* __restrict__ depths,
                  float* __restrict__ out) {
    __shared__ float4 s_r0[G_COUNT];               // {mx,my,A=.5a*l2e,C=.5c*l2e} 32KB
    __shared__ float4 s_r1[G_COUNT];               // {B=b*l2e, col r,g,b}        32KB
    __shared__ float2 s_r2[G_COUNT];               // {o, l2o=log2(255o)}         16KB
    __shared__ unsigned long long s_key[G_COUNT];  //                             16KB
    __shared__ int s_perm[G_COUNT];                //                              8KB
    __shared__ int s_cnt;

    const int tid = threadIdx.x;
    const int wv = tid >> 6;
    const int lane = tid & 63;
    const int tile = blockIdx.x;                   // 16x16 tiles of 8x8 px
    const int tx = tile & 15;
    const int ty = tile >> 4;

    if (tid == 0) s_cnt = 0;
    __syncthreads();

    const float bx0 = (float)(tx * 8) + 0.5f;
    const float bx1 = (float)(tx * 8 + 7) + 0.5f;
    const float by0 = (float)(ty * 8) + 0.5f;
    const float by1 = (float)(ty * 8 + 7) + 0.5f;

    // ---- Phase 1: cull + compact (order fixed later by sort) ----
    for (int k = 0; k < G_COUNT; k += 256) {
        int gi = k + tid;
        float2 m = ((const float2*)means2d)[gi];     // coalesced 8B
        float a = conics[3 * gi + 0];
        float b = conics[3 * gi + 1];
        float c = conics[3 * gi + 2];
        float o = opac[gi];
        float d = depths[gi];

        float l2o = __log2f(255.0f * o);             // o >= 0.05 -> positive
        // Conservative cull radius: sigma >= 0.5*lmin*|d|^2 -> alpha < 1/255
        // outside r2 = 2*ln(255 o)/lmin; 2% inflation for fp slop.
        float half_tr = 0.5f * (a + c);
        float hd = 0.5f * (a - c);
        float lmin = half_tr - sqrtf(hd * hd + b * b);
        float r2 = (lmin > 1e-12f) ? ((2.04f * LN2) * l2o / lmin) : 1e30f;

        float ddx = fmaxf(fmaxf(bx0 - m.x, m.x - bx1), 0.0f);
        float ddy = fmaxf(fmaxf(by0 - m.y, m.y - by1), 0.0f);
        bool pass = (ddx * ddx + ddy * ddy) <= r2;

        unsigned long long msk = __ballot(pass);
        int npass = __popcll(msk);
        int prefix = __builtin_amdgcn_mbcnt_hi((unsigned)(msk >> 32),
                     __builtin_amdgcn_mbcnt_lo((unsigned)msk, 0));
        int wbase = 0;
        if (lane == 0 && npass) wbase = atomicAdd(&s_cnt, npass);
        wbase = __shfl(wbase, 0);
        if (pass) {
            int pos = wbase + prefix;
            s_r0[pos] = make_float4(m.x, m.y, 0.5f * a * LOG2E, 0.5f * c * LOG2E);
            s_r1[pos] = make_float4(b * LOG2E,
                                    colors[3 * gi + 0],
                                    colors[3 * gi + 1],
                                    colors[3 * gi + 2]);
            s_r2[pos] = make_float2(o, l2o);
            // depths > 0: raw float bits preserve order; idx makes key unique
            // and the sort stable (matches argsort(depths, stable)).
            s_key[pos] = ((unsigned long long)__float_as_uint(d) << 32) | (unsigned)gi;
        }
    }
    __syncthreads();

    // ---- Phase 2: rank sort survivors -> s_perm[rank] = compact slot ----
    const int n = s_cnt;
    const int npad = (n + 31) & ~31;
    for (int s = tid; s < n; s += 256) {
        unsigned long long key = s_key[s];
        int rk = 0;
#pragma unroll 4
        for (int j = 0; j < n; ++j) {             // broadcast reads, conflict-free
            rk += (s_key[j] < key) ? 1 : 0;
        }
        s_perm[rk] = s;                           // unique keys -> permutation
    }
    for (int i = n + tid; i < npad; i += 256) s_perm[i] = n;   // pad -> dummy
    if (tid == 0 && n < G_COUNT) {                // dummy record (zero alpha)
        s_r0[n] = make_float4(0.f, 0.f, 0.f, 0.f);
        s_r1[n] = make_float4(0.f, 0.f, 0.f, 0.f);
        s_r2[n] = make_float2(0.f, -1.f);         // s2(=0) > l2o(-1) -> al = 0
    }
    __syncthreads();

    // ---- Phase 3: quad-slot composite, 32 gaussians/group ----
    const int slot = lane & 3;                    // gaussian slot within quad
    const int p = wv * 16 + (lane >> 2);          // pixel 0..63 of the tile
    const int pxi = tx * 8 + (p & 7);
    const int pyi = ty * 8 + (p >> 3);
    const float px = (float)pxi + 0.5f;
    const float py = (float)pyi + 0.5f;

    float T = 1.0f;
    float accr = 0.0f, accg = 0.0f, accb = 0.0f;

    for (int base = 0; base < npad; base += 32) {
        // Stage the whole group: 8 perm reads, then 24 record reads; one
        // lgkmcnt wait amortized over the group.
        int pidx[8];
        float4 lp[8], lc[8];
        float2 lo[8];
#pragma unroll
        for (int jj = 0; jj < 8; ++jj) {
            pidx[jj] = s_perm[base + jj * 4 + slot];
        }
#pragma unroll
        for (int jj = 0; jj < 8; ++jj) {
            lp[jj] = s_r0[pidx[jj]];
            lc[jj] = s_r1[pidx[jj]];
            lo[jj] = s_r2[pidx[jj]];
        }
#pragma unroll
        for (int jj = 0; jj < 8; ++jj) {
            float4 pp = lp[jj];
            float4 c = lc[jj];
            float2 o2 = lo[jj];

            float dx = px - pp.x;
            float dy = py - pp.y;
            float s2 = fmaf(pp.z * dx, dx, fmaf(pp.w * dy, dy, (c.x * dx) * dy));
#if __has_builtin(__builtin_amdgcn_exp2f)
            float e = __builtin_amdgcn_exp2f(-s2);
#else
            float e = __expf(-s2 * LN2);
#endif
            float al = fminf(o2.x * e, ALPHA_MAX);
            al = (s2 < 0.0f || s2 > o2.y) ? 0.0f : al;
            float om = 1.0f - al;

            // Quad prefix products via DPP (VALU latency, not LDS).
            float x1 = qperm<0xB1>(om);
            float p2 = om * x1;
            float x2 = qperm<0x4E>(p2);
            float qp = p2 * x2;                   // quad product (bit-uniform)
            float pre = (slot & 1) ? x1 : 1.0f;
            if (slot & 2) pre *= x2;              // prefix: 1, o0, o0o1, o0o1o2

            float Tb = T * pre;                   // short serial T-chain
            float Tn = Tb * om;
            float w = (Tn >= T_THR) ? al * Tb : 0.0f;
            accr = fmaf(w, c.y, accr);
            accg = fmaf(w, c.z, accg);
            accb = fmaf(w, c.w, accb);
            T *= qp;
        }
        if (__ballot(T >= T_THR) == 0ULL) break;
    }

    // Quad-reduce rgb via DPP; lanes 0..2 of each quad store channels r,g,b.
    float sr = accr + qperm<0xB1>(accr); sr += qperm<0x4E>(sr);
    float sg = accg + qperm<0xB1>(accg); sg += qperm<0x4E>(sg);
    float sb = accb + qperm<0xB1>(accb); sb += qperm<0x4E>(sb);
    if (slot < 3) {
        float v = (slot == 0) ? sr : ((slot == 1) ? sg : sb);
        out[((size_t)pyi * IMG_W + pxi) * 3 + slot] = v;
    }
}

extern "C" void kernel_launch(void* const* d_in, const int* in_sizes, int n_in,
                              void* d_out, int out_size, void* d_ws, size_t ws_size,
                              hipStream_t stream) {
    const float* means2d = (const float*)d_in[0];
    const float* conics  = (const float*)d_in[1];
    const float* colors  = (const float*)d_in[2];
    const float* opac    = (const float*)d_in[3];
    const float* depths  = (const float*)d_in[4];
    float* out = (float*)d_out;

    raster_fused<<<256, 256, 0, stream>>>(means2d, conics, colors, opac, depths, out);
}

// Round 8
// 18.932 us; speedup vs baseline: 19.2845x; 1.0741x over previous
//
#include <hip/hip_runtime.h>
#include <hip/hip_bf16.h>

#define G_COUNT 2048
#define IMG_W 128
#define T_THR 1e-4f
#define ALPHA_MAX 0.99f
#define LOG2E 1.4426950408889634f
#define LN2 0.6931471805599453f

__device__ __forceinline__ float fexp2(float x) {
#if __has_builtin(__builtin_amdgcn_exp2f)
    return __builtin_amdgcn_exp2f(x);
#else
    return __expf(x * LN2);
#endif
}

// Single fused kernel: 256 blocks x 512 threads (8 waves), one 8x8 tile/block.
// Phase 1: cull from raw inputs (L2-resident), atomic compaction into LDS
//          (order fixed by the sort -> output deterministic).
// Phase 2: rank sort survivors by unique (depth_bits, idx) key -> perm.
// Phase 3: segmented composite. Compositing is associative:
//          rgb = sum_s rgb_s * prod_{t<s} Tt_t. Pass A: wave w computes its
//          segment's transmittance product per pixel (lane=pixel). Pass B:
//          wave w starts from the exact global prefix and applies the
//          reference's Tn>=1e-4 validity test item by item.
__global__ __launch_bounds__(512)
void raster_fused(const float* __restrict__ means2d,
                  const float* __restrict__ conics,
                  const float* __restrict__ colors,
                  const float* __restrict__ opac,
                  const float* __restrict__ depths,
                  float* __restrict__ out) {
    __shared__ float4 s_r0[G_COUNT + 1];            // {mx,my,A=.5a*l2e,C=.5c*l2e}
    __shared__ float4 s_r1[G_COUNT + 1];            // {B=b*l2e, col r,g,b}
    __shared__ float2 s_r2[G_COUNT + 1];            // {o, l2o=log2(255o)}
    __shared__ unsigned long long s_key[G_COUNT];
    __shared__ int s_perm[G_COUNT];
    __shared__ float s_T[7][64];                    // per-wave segment transmittance
    __shared__ float s_rgb[8][192];                 // per-wave partial rgb
    __shared__ int s_cnt;

    const int tid = threadIdx.x;
    const int wv = tid >> 6;                        // 0..7
    const int lane = tid & 63;
    const int tile = blockIdx.x;                    // 16x16 tiles of 8x8 px
    const int tx = tile & 15;
    const int ty = tile >> 4;

    if (tid == 0) s_cnt = 0;
    __syncthreads();

    const float bx0 = (float)(tx * 8) + 0.5f;
    const float bx1 = (float)(tx * 8 + 7) + 0.5f;
    const float by0 = (float)(ty * 8) + 0.5f;
    const float by1 = (float)(ty * 8 + 7) + 0.5f;

    // ---- Phase 1: cull + compact ----
    for (int k = 0; k < G_COUNT; k += 512) {
        int gi = k + tid;
        float2 m = ((const float2*)means2d)[gi];
        float a = conics[3 * gi + 0];
        float b = conics[3 * gi + 1];
        float c = conics[3 * gi + 2];
        float o = opac[gi];
        float d = depths[gi];

        float l2o = __log2f(255.0f * o);            // o >= 0.05 -> positive
        // Conservative cull: sigma >= 0.5*lmin*|d|^2 -> alpha < 1/255 outside
        // r2 = 2*ln(255 o)/lmin; 2% inflation for fp slop.
        float half_tr = 0.5f * (a + c);
        float hd = 0.5f * (a - c);
        float lmin = half_tr - sqrtf(hd * hd + b * b);
        float r2 = (lmin > 1e-12f) ? ((2.04f * LN2) * l2o / lmin) : 1e30f;

        float ddx = fmaxf(fmaxf(bx0 - m.x, m.x - bx1), 0.0f);
        float ddy = fmaxf(fmaxf(by0 - m.y, m.y - by1), 0.0f);
        bool pass = (ddx * ddx + ddy * ddy) <= r2;

        unsigned long long msk = __ballot(pass);
        int prefix = __builtin_amdgcn_mbcnt_hi((unsigned)(msk >> 32),
                     __builtin_amdgcn_mbcnt_lo((unsigned)msk, 0));
        int wbase = 0;
        if (lane == 0) wbase = atomicAdd(&s_cnt, __popcll(msk));
        wbase = __shfl(wbase, 0);
        if (pass) {
            int pos = wbase + prefix;
            s_r0[pos] = make_float4(m.x, m.y, 0.5f * a * LOG2E, 0.5f * c * LOG2E);
            s_r1[pos] = make_float4(b * LOG2E,
                                    colors[3 * gi + 0],
                                    colors[3 * gi + 1],
                                    colors[3 * gi + 2]);
            s_r2[pos] = make_float2(o, l2o);
            // depths > 0: raw bits preserve order; idx -> unique & stable.
            s_key[pos] = ((unsigned long long)__float_as_uint(d) << 32) | (unsigned)gi;
        }
    }
    __syncthreads();

    // ---- Phase 2: rank sort -> s_perm[rank] = compact slot ----
    const int n = s_cnt;
    const int npad = (n + 63) & ~63;                // 8 segments, each mult of 8
    const int seg = npad >> 3;
    for (int s = tid; s < n; s += 512) {
        unsigned long long key = s_key[s];
        int rk = 0;
#pragma unroll 4
        for (int j = 0; j < n; ++j) {               // uniform addr -> broadcast
            rk += (s_key[j] < key) ? 1 : 0;
        }
        s_perm[rk] = s;                             // unique keys -> permutation
    }
    for (int i = n + tid; i < npad; i += 512) s_perm[i] = n;
    if (tid == 0 && n < G_COUNT) {                  // dummy record: alpha == 0
        s_r0[n] = make_float4(0.f, 0.f, 0.f, 0.f);
        s_r1[n] = make_float4(0.f, 0.f, 0.f, 0.f);
        s_r2[n] = make_float2(0.f, -1.f);           // s2(=0) > l2o(-1) -> al=0
    }
    __syncthreads();

    // ---- Phase 3: segmented composite; lane = pixel ----
    const int pxi = tx * 8 + (lane & 7);
    const int pyi = ty * 8 + (lane >> 3);
    const float px = (float)pxi + 0.5f;
    const float py = (float)pyi + 0.5f;
    const int i0 = wv * seg;

    // Pass A: segment transmittance product (wave 7's is never consumed).
    if (wv < 7) {
        float Tw = 1.0f;
        for (int j = 0; j < seg; ++j) {
            int p = s_perm[i0 + j];
            float4 r0 = s_r0[p];
            float B = s_r1[p].x;
            float2 o2 = s_r2[p];
            float dx = px - r0.x;
            float dy = py - r0.y;
            float s2 = fmaf(r0.z * dx, dx, fmaf(r0.w * dy, dy, (B * dx) * dy));
            float al = fminf(o2.x * fexp2(-s2), ALPHA_MAX);
            al = (s2 < 0.0f || s2 > o2.y) ? 0.0f : al;
            Tw *= 1.0f - al;
        }
        s_T[wv][lane] = Tw;
    }
    __syncthreads();

    // Exact global prefix for this wave's segment start.
    float pre = 1.0f;
    for (int t = 0; t < wv; ++t) pre *= s_T[t][lane];

    // Pass B: exact composite with the reference's validity test.
    float accr = 0.0f, accg = 0.0f, accb = 0.0f;
    if (__ballot(pre >= T_THR) != 0ULL) {           // skip fully-dead segments
        float T = pre;
        for (int jb = 0; jb < seg; jb += 8) {
#pragma unroll
            for (int j = 0; j < 8; ++j) {
                int p = s_perm[i0 + jb + j];
                float4 r0 = s_r0[p];
                float4 r1 = s_r1[p];
                float2 o2 = s_r2[p];
                float dx = px - r0.x;
                float dy = py - r0.y;
                float s2 = fmaf(r0.z * dx, dx, fmaf(r0.w * dy, dy, (r1.x * dx) * dy));
                float al = fminf(o2.x * fexp2(-s2), ALPHA_MAX);
                al = (s2 < 0.0f || s2 > o2.y) ? 0.0f : al;
                float om = 1.0f - al;
                float Tn = T * om;
                float w = (Tn >= T_THR) ? al * T : 0.0f;
                accr = fmaf(w, r1.y, accr);
                accg = fmaf(w, r1.z, accg);
                accb = fmaf(w, r1.w, accb);
                T = Tn;
            }
            if (__ballot(T >= T_THR) == 0ULL) break;
        }
    }
    s_rgb[wv][lane * 3 + 0] = accr;
    s_rgb[wv][lane * 3 + 1] = accg;
    s_rgb[wv][lane * 3 + 2] = accb;
    __syncthreads();

    // ---- Final reduce: 192 outputs (64 px x 3 ch) ----
    if (tid < 192) {
        float sum = 0.0f;
#pragma unroll
        for (int w = 0; w < 8; ++w) sum += s_rgb[w][tid];
        int p2 = tid / 3;
        int ch = tid - p2 * 3;
        int opx = tx * 8 + (p2 & 7);
        int opy = ty * 8 + (p2 >> 3);
        out[((size_t)opy * IMG_W + opx) * 3 + ch] = sum;
    }
}

extern "C" void kernel_launch(void* const* d_in, const int* in_sizes, int n_in,
                              void* d_out, int out_size, void* d_ws, size_t ws_size,
                              hipStream_t stream) {
    const float* means2d = (const float*)d_in[0];
    const float* conics  = (const float*)d_in[1];
    const float* colors  = (const float*)d_in[2];
    const float* opac    = (const float*)d_in[3];
    const float* depths  = (const float*)d_in[4];
    float* out = (float*)d_out;

    raster_fused<<<256, 512, 0, stream>>>(means2d, conics, colors, opac, depths, out);
}

// Round 9
// 14.483 us; speedup vs baseline: 25.2090x; 1.3072x over previous
//
#include <hip/hip_runtime.h>
#include <hip/hip_bf16.h>

#define G_COUNT 2048
#define IMG_W 128
#define T_THR 1e-4f
#define ALPHA_MAX 0.99f
#define LOG2E 1.4426950408889634f

__device__ __forceinline__ float fexp2(float x) {
#if __has_builtin(__builtin_amdgcn_exp2f)
    return __builtin_amdgcn_exp2f(x);
#else
    return __expf(x * 0.6931471805599453f);
#endif
}

__device__ __forceinline__ float frcp(float x) {
#if __has_builtin(__builtin_amdgcn_rcpf)
    return __builtin_amdgcn_rcpf(x);
#else
    return 1.0f / x;
#endif
}

__device__ __forceinline__ float clampf(float x, float lo, float hi) {
    return fminf(fmaxf(x, lo), hi);
}

// Single fused kernel: 256 blocks x 512 threads (8 waves), one 8x8 tile/block.
// Phase 1: exact conic-box cull (min of the PD quadratic over the tile rect),
//          wave-aggregated atomic compaction into LDS (order fixed by sort).
// Phase 2: stable rank sort of survivors by unique (depth_bits, idx) key.
// Phase 3: group-interleaved composite: per 64-item group, wave w evaluates
//          items w*8..w*8+7 once (alphas + local prefix products in regs),
//          publishes the 8-product, one barrier, exact cross-wave prefix,
//          weighted accumulation; T_global *= group product (bit-uniform
//          across waves); ballot early-exit per group. Validity (Tn>=1e-4)
//          is monotone, so dead items past the cut contribute exactly 0.
__global__ __launch_bounds__(512)
void raster_fused(const float* __restrict__ means2d,
                  const float* __restrict__ conics,
                  const float* __restrict__ colors,
                  const float* __restrict__ opac,
                  const float* __restrict__ depths,
                  float* __restrict__ out) {
    __shared__ float4 s_r0[G_COUNT + 1];            // {mx,my,A=.5a*l2e,C=.5c*l2e}
    __shared__ float4 s_r1[G_COUNT + 1];            // {B=b*l2e, col r,g,b}
    __shared__ float2 s_r2[G_COUNT + 1];            // {o, l2o=log2(255o)}
    __shared__ unsigned long long s_key[G_COUNT];
    __shared__ int s_perm[G_COUNT];
    __shared__ float s_T[2][8][64];                 // dbuf group products
    __shared__ float s_rgb[8][192];
    __shared__ int s_cnt;

    const int tid = threadIdx.x;
    const int wv = tid >> 6;                        // 0..7
    const int lane = tid & 63;
    const int tile = blockIdx.x;                    // 16x16 tiles of 8x8 px
    const int tx = tile & 15;
    const int ty = tile >> 4;

    if (tid == 0) s_cnt = 0;
    __syncthreads();

    const float bx0 = (float)(tx * 8) + 0.5f;
    const float bx1 = (float)(tx * 8 + 7) + 0.5f;
    const float by0 = (float)(ty * 8) + 0.5f;
    const float by1 = (float)(ty * 8 + 7) + 0.5f;

    // ---- Phase 1: exact-box cull + compact ----
    for (int k = 0; k < G_COUNT; k += 512) {
        int gi = k + tid;
        float2 m = ((const float2*)means2d)[gi];
        float a = conics[3 * gi + 0];
        float b = conics[3 * gi + 1];
        float c = conics[3 * gi + 2];
        float o = opac[gi];
        float d = depths[gi];

        float A = 0.5f * a * LOG2E;                 // s2 = A dx^2 + C dy^2 + B dx dy
        float C = 0.5f * c * LOG2E;                 //    = sigma * log2(e)
        float B = b * LOG2E;
        float l2o = __log2f(255.0f * o);            // o >= 0.05 -> positive

        // min of s2 over the tile rect (conic PD: interior min at the mean,
        // else on the boundary; each edge is a 1-D quadratic, clamp vertex).
        float lx = bx0 - m.x, hx = bx1 - m.x;
        float ly = by0 - m.y, hy = by1 - m.y;
        bool inside = (lx <= 0.0f) & (hx >= 0.0f) & (ly <= 0.0f) & (hy >= 0.0f);
        float rC = frcp(C), rA = frcp(A);
        float d1 = clampf(-0.5f * B * lx * rC, ly, hy);
        float d2 = clampf(-0.5f * B * hx * rC, ly, hy);
        float d3 = clampf(-0.5f * B * ly * rA, lx, hx);
        float d4 = clampf(-0.5f * B * hy * rA, lx, hx);
        float m1 = fmaf(A * lx, lx, fmaf(C * d1, d1, (B * lx) * d1));
        float m2 = fmaf(A * hx, hx, fmaf(C * d2, d2, (B * hx) * d2));
        float m3 = fmaf(A * d3, d3, fmaf(C * ly, ly, (B * d3) * ly));
        float m4 = fmaf(A * d4, d4, fmaf(C * hy, hy, (B * d4) * hy));
        float minv = fminf(fminf(m1, m2), fminf(m3, m4));
        bool pass = inside || (minv <= l2o + 0.01f);   // conservative margin

        unsigned long long msk = __ballot(pass);
        int prefix = __builtin_amdgcn_mbcnt_hi((unsigned)(msk >> 32),
                     __builtin_amdgcn_mbcnt_lo((unsigned)msk, 0));
        int wbase = 0;
        if (lane == 0) wbase = atomicAdd(&s_cnt, __popcll(msk));
        wbase = __shfl(wbase, 0);
        if (pass) {
            int pos = wbase + prefix;
            s_r0[pos] = make_float4(m.x, m.y, A, C);
            s_r1[pos] = make_float4(B,
                                    colors[3 * gi + 0],
                                    colors[3 * gi + 1],
                                    colors[3 * gi + 2]);
            s_r2[pos] = make_float2(o, l2o);
            // depths > 0: raw bits preserve order; idx -> unique & stable.
            s_key[pos] = ((unsigned long long)__float_as_uint(d) << 32) | (unsigned)gi;
        }
    }
    __syncthreads();

    // ---- Phase 2: rank sort -> s_perm[rank] = compact slot ----
    const int n = s_cnt;
    const int npad = (n + 63) & ~63;                // groups of 64
    for (int s = tid; s < n; s += 512) {
        unsigned long long key = s_key[s];
        int rk = 0;
#pragma unroll 4
        for (int j = 0; j < n; ++j) {               // uniform addr -> broadcast
            rk += (s_key[j] < key) ? 1 : 0;
        }
        s_perm[rk] = s;                             // unique keys -> permutation
    }
    for (int i = n + tid; i < npad; i += 512) s_perm[i] = n;
    if (tid == 0 && n < G_COUNT) {                  // dummy record: alpha == 0
        s_r0[n] = make_float4(0.f, 0.f, 0.f, 0.f);
        s_r1[n] = make_float4(0.f, 0.f, 0.f, 0.f);
        s_r2[n] = make_float2(0.f, -1.f);           // s2(=0) > l2o(-1) -> al=0
    }
    __syncthreads();

    // ---- Phase 3: group-interleaved composite; lane = pixel ----
    const int pxi = tx * 8 + (lane & 7);
    const int pyi = ty * 8 + (lane >> 3);
    const float px = (float)pxi + 0.5f;
    const float py = (float)pyi + 0.5f;

    float T = 1.0f;
    float accr = 0.0f, accg = 0.0f, accb = 0.0f;
    const int ngroups = npad >> 6;

    for (int g = 0; g < ngroups; ++g) {
        const int base = g * 64 + wv * 8;
        int pidx[8];
        float4 r0[8], r1[8];
        float2 o2[8];
#pragma unroll
        for (int j = 0; j < 8; ++j) pidx[j] = s_perm[base + j];
#pragma unroll
        for (int j = 0; j < 8; ++j) {
            r0[j] = s_r0[pidx[j]];                  // uniform addr -> broadcast
            r1[j] = s_r1[pidx[j]];
            o2[j] = s_r2[pidx[j]];
        }
        float al[8], cum[8];
        float run = 1.0f;
#pragma unroll
        for (int j = 0; j < 8; ++j) {
            float dx = px - r0[j].x;
            float dy = py - r0[j].y;
            float s2 = fmaf(r0[j].z * dx, dx, fmaf(r0[j].w * dy, dy, (r1[j].x * dx) * dy));
            float a = fminf(o2[j].x * fexp2(-s2), ALPHA_MAX);
            a = (s2 < 0.0f || s2 > o2[j].y) ? 0.0f : a;
            al[j] = a;
            run *= 1.0f - a;
            cum[j] = run;                           // local prefix incl. item j
        }
        s_T[g & 1][wv][lane] = run;
        __syncthreads();

        float pre = 1.0f, full = 1.0f;
#pragma unroll
        for (int t = 0; t < 8; ++t) {
            float v = s_T[g & 1][t][lane];
            full *= v;                              // same order all waves -> bit-uniform
            if (t < wv) pre *= v;
        }
        float Tw0 = T * pre;                        // exact global prefix at wave start
#pragma unroll
        for (int j = 0; j < 8; ++j) {
            float Tb = Tw0 * ((j == 0) ? 1.0f : cum[j - 1]);
            float Tn = Tw0 * cum[j];
            float w = (Tn >= T_THR) ? al[j] * Tb : 0.0f;
            accr = fmaf(w, r1[j].y, accr);
            accg = fmaf(w, r1[j].z, accg);
            accb = fmaf(w, r1[j].w, accb);
        }
        T *= full;                                  // bit-uniform across waves
        // Uniform decision (same T values in every wave) -> safe early exit;
        // s_T is double-buffered so no trailing barrier is needed.
        if (__ballot(T >= T_THR) == 0ULL) break;
    }

    s_rgb[wv][lane * 3 + 0] = accr;
    s_rgb[wv][lane * 3 + 1] = accg;
    s_rgb[wv][lane * 3 + 2] = accb;
    __syncthreads();

    // ---- Final reduce: 192 outputs (64 px x 3 ch) ----
    if (tid < 192) {
        float sum = 0.0f;
#pragma unroll
        for (int w = 0; w < 8; ++w) sum += s_rgb[w][tid];
        int p2 = tid / 3;
        int ch = tid - p2 * 3;
        int opx = tx * 8 + (p2 & 7);
        int opy = ty * 8 + (p2 >> 3);
        out[((size_t)opy * IMG_W + opx) * 3 + ch] = sum;
    }
}

extern "C" void kernel_launch(void* const* d_in, const int* in_sizes, int n_in,
                              void* d_out, int out_size, void* d_ws, size_t ws_size,
                              hipStream_t stream) {
    const float* means2d = (const float*)d_in[0];
    const float* conics  = (const float*)d_in[1];
    const float* colors  = (const float*)d_in[2];
    const float* opac    = (const float*)d_in[3];
    const float* depths  = (const float*)d_in[4];
    float* out = (float*)d_out;

    raster_fused<<<256, 512, 0, stream>>>(means2d, conics, colors, opac, depths, out);
}

// Round 10
// 14.145 us; speedup vs baseline: 25.8112x; 1.0239x over previous
//
#include <hip/hip_runtime.h>
#include <hip/hip_bf16.h>
#include <hip/hip_fp16.h>

#define G_COUNT 2048
#define IMG_W 128
#define T_THR 1e-4f
#define ALPHA_MAX 0.99f
#define LOG2E 1.4426950408889634f
#define INV255 0.003921568627451f

__device__ __forceinline__ float fexp2(float x) {
#if __has_builtin(__builtin_amdgcn_exp2f)
    return __builtin_amdgcn_exp2f(x);
#else
    return __expf(x * 0.6931471805599453f);
#endif
}

__device__ __forceinline__ float frcp(float x) {
#if __has_builtin(__builtin_amdgcn_rcpf)
    return __builtin_amdgcn_rcpf(x);
#else
    return 1.0f / x;
#endif
}

__device__ __forceinline__ float clampf(float x, float lo, float hi) {
    return fminf(fmaxf(x, lo), hi);
}

// Single fused kernel: 256 blocks x 512 threads (8 waves), one 8x8 tile/block.
// Records are packed to 32 B (2 x b128): {mx,my,A,C | B,l2o,pk(r,g),pk(b,-)}.
// alpha = exp2(l2o - s2)/255  (== o*exp(-sigma) to ~1e-6; alpha<1/255 <=> s2>l2o),
// so opacity needs no separate slot; colors are f16 (<=5e-4 abs err).
__global__ __launch_bounds__(512)
void raster_fused(const float* __restrict__ means2d,
                  const float* __restrict__ conics,
                  const float* __restrict__ colors,
                  const float* __restrict__ opac,
                  const float* __restrict__ depths,
                  float* __restrict__ out) {
    __shared__ alignas(16) float4 s_rec[2 * (G_COUNT + 1)];      // packed records
    __shared__ alignas(16) unsigned long long s_key[G_COUNT + 2];
    __shared__ alignas(16) int s_perm[G_COUNT];
    __shared__ float s_T[2][8][64];                  // dbuf group products
    __shared__ float s_rgb[8][192];
    __shared__ int s_cnt;

    const int tid = threadIdx.x;
    const int wv = tid >> 6;                         // 0..7
    const int lane = tid & 63;
    const int tile = blockIdx.x;                     // 16x16 tiles of 8x8 px
    const int tx = tile & 15;
    const int ty = tile >> 4;

    if (tid == 0) s_cnt = 0;
    __syncthreads();

    const float bx0 = (float)(tx * 8) + 0.5f;
    const float bx1 = (float)(tx * 8 + 7) + 0.5f;
    const float by0 = (float)(ty * 8) + 0.5f;
    const float by1 = (float)(ty * 8 + 7) + 0.5f;

    // ---- Phase 1: exact conic-box cull + compact packed records ----
    for (int k = 0; k < G_COUNT; k += 512) {
        int gi = k + tid;
        float2 m = ((const float2*)means2d)[gi];
        float a = conics[3 * gi + 0];
        float b = conics[3 * gi + 1];
        float c = conics[3 * gi + 2];
        float o = opac[gi];
        float d = depths[gi];

        float A = 0.5f * a * LOG2E;                  // s2 = A dx^2 + C dy^2 + B dx dy
        float C = 0.5f * c * LOG2E;                  //    = sigma * log2(e)
        float B = b * LOG2E;
        float l2o = __log2f(255.0f * o);             // o >= 0.05 -> positive

        // min of s2 over the tile rect: interior (mean inside) else boundary;
        // each edge is a 1-D quadratic, clamp its vertex to the edge range.
        float lx = bx0 - m.x, hx = bx1 - m.x;
        float ly = by0 - m.y, hy = by1 - m.y;
        bool inside = (lx <= 0.0f) & (hx >= 0.0f) & (ly <= 0.0f) & (hy >= 0.0f);
        float rC = frcp(C), rA = frcp(A);
        float d1 = clampf(-0.5f * B * lx * rC, ly, hy);
        float d2 = clampf(-0.5f * B * hx * rC, ly, hy);
        float d3 = clampf(-0.5f * B * ly * rA, lx, hx);
        float d4 = clampf(-0.5f * B * hy * rA, lx, hx);
        float m1 = fmaf(A * lx, lx, fmaf(C * d1, d1, (B * lx) * d1));
        float m2 = fmaf(A * hx, hx, fmaf(C * d2, d2, (B * hx) * d2));
        float m3 = fmaf(A * d3, d3, fmaf(C * ly, ly, (B * d3) * ly));
        float m4 = fmaf(A * d4, d4, fmaf(C * hy, hy, (B * d4) * hy));
        float minv = fminf(fminf(m1, m2), fminf(m3, m4));
        bool pass = inside || (minv <= l2o + 0.01f);    // conservative margin

        unsigned long long msk = __ballot(pass);
        int prefix = __builtin_amdgcn_mbcnt_hi((unsigned)(msk >> 32),
                     __builtin_amdgcn_mbcnt_lo((unsigned)msk, 0));
        int wbase = 0;
        if (lane == 0) wbase = atomicAdd(&s_cnt, __popcll(msk));
        wbase = __shfl(wbase, 0);
        if (pass) {
            int pos = wbase + prefix;
            __half2 rg = __floats2half2_rn(colors[3 * gi + 0], colors[3 * gi + 1]);
            __half2 bz = __floats2half2_rn(colors[3 * gi + 2], 0.0f);
            s_rec[2 * pos + 0] = make_float4(m.x, m.y, A, C);
            s_rec[2 * pos + 1] = make_float4(B, l2o,
                                             __uint_as_float(*(unsigned*)&rg),
                                             __uint_as_float(*(unsigned*)&bz));
            // depths > 0: raw bits preserve order; idx -> unique & stable.
            s_key[pos] = ((unsigned long long)__float_as_uint(d) << 32) | (unsigned)gi;
        }
    }
    __syncthreads();

    // ---- Phase 2: rank sort -> s_perm[rank] = compact slot ----
    const int n = s_cnt;
    const int npad = (n + 63) & ~63;                 // groups of 64
    if (tid < 2) s_key[n + tid] = ~0ULL;             // pair-read padding
    __syncthreads();
    const int npairs = (n + 1) >> 1;
    for (int s = tid; s < n; s += 512) {
        unsigned long long key = s_key[s];
        int rk = 0;
        const ulonglong2* kp = (const ulonglong2*)s_key;
#pragma unroll 4
        for (int jj = 0; jj < npairs; ++jj) {        // b128: 2 keys per read
            ulonglong2 k2 = kp[jj];
            rk += (k2.x < key) ? 1 : 0;
            rk += (k2.y < key) ? 1 : 0;
        }
        s_perm[rk] = s;                              // unique keys -> permutation
    }
    for (int i = n + tid; i < npad; i += 512) s_perm[i] = n;
    if (tid == 0 && n < G_COUNT) {                   // dummy record: alpha == 0
        s_rec[2 * n + 0] = make_float4(0.f, 0.f, 0.f, 0.f);
        s_rec[2 * n + 1] = make_float4(0.f, -1.f, 0.f, 0.f);  // l2o=-1 -> al=0
    }
    __syncthreads();

    // ---- Phase 3: group-interleaved composite; lane = pixel ----
    const int pxi = tx * 8 + (lane & 7);
    const int pyi = ty * 8 + (lane >> 3);
    const float px = (float)pxi + 0.5f;
    const float py = (float)pyi + 0.5f;

    float T = 1.0f;
    float accr = 0.0f, accg = 0.0f, accb = 0.0f;
    const int ngroups = npad >> 6;

    for (int g = 0; g < ngroups; ++g) {
        const int base = g * 64 + wv * 8;
        // Batched perm read: 8 ints = 2 x b128.
        const int4* pp4 = (const int4*)(s_perm + base);
        int4 pa = pp4[0], pb = pp4[1];
        int pidx[8] = {pa.x, pa.y, pa.z, pa.w, pb.x, pb.y, pb.z, pb.w};

        float4 ra[8], rb[8];
#pragma unroll
        for (int j = 0; j < 8; ++j) {
            ra[j] = s_rec[2 * pidx[j] + 0];          // uniform addr -> broadcast
            rb[j] = s_rec[2 * pidx[j] + 1];
        }
        float al[8], cum[8];
        float run = 1.0f;
#pragma unroll
        for (int j = 0; j < 8; ++j) {
            float dx = px - ra[j].x;
            float dy = py - ra[j].y;
            float s2 = fmaf(ra[j].z * dx, dx, fmaf(ra[j].w * dy, dy, (rb[j].x * dx) * dy));
            float a = fminf(fexp2(rb[j].y - s2) * INV255, ALPHA_MAX);
            a = (s2 < 0.0f || s2 > rb[j].y) ? 0.0f : a;
            al[j] = a;
            run *= 1.0f - a;
            cum[j] = run;                            // local prefix incl. item j
        }
        s_T[g & 1][wv][lane] = run;
        __syncthreads();

        float pre = 1.0f, full = 1.0f;
#pragma unroll
        for (int t = 0; t < 8; ++t) {
            float v = s_T[g & 1][t][lane];
            full *= v;                               // same order everywhere -> bit-uniform
            if (t < wv) pre *= v;
        }
        float Tw0 = T * pre;                         // exact global prefix at wave start
#pragma unroll
        for (int j = 0; j < 8; ++j) {
            float Tb = Tw0 * ((j == 0) ? 1.0f : cum[j - 1]);
            float Tn = Tw0 * cum[j];
            float w = (Tn >= T_THR) ? al[j] * Tb : 0.0f;
            unsigned urg = __float_as_uint(rb[j].z);
            unsigned ub = __float_as_uint(rb[j].w);
            float2 rg = __half22float2(*(__half2*)&urg);
            float2 b2 = __half22float2(*(__half2*)&ub);
            accr = fmaf(w, rg.x, accr);
            accg = fmaf(w, rg.y, accg);
            accb = fmaf(w, b2.x, accb);
        }
        T *= full;                                   // bit-uniform across waves
        // Uniform decision -> safe early exit; s_T double-buffered, no extra barrier.
        if (__ballot(T >= T_THR) == 0ULL) break;
    }

    s_rgb[wv][lane * 3 + 0] = accr;
    s_rgb[wv][lane * 3 + 1] = accg;
    s_rgb[wv][lane * 3 + 2] = accb;
    __syncthreads();

    // ---- Final reduce: 192 outputs (64 px x 3 ch) ----
    if (tid < 192) {
        float sum = 0.0f;
#pragma unroll
        for (int w = 0; w < 8; ++w) sum += s_rgb[w][tid];
        int p2 = tid / 3;
        int ch = tid - p2 * 3;
        int opx = tx * 8 + (p2 & 7);
        int opy = ty * 8 + (p2 >> 3);
        out[((size_t)opy * IMG_W + opx) * 3 + ch] = sum;
    }
}

extern "C" void kernel_launch(void* const* d_in, const int* in_sizes, int n_in,
                              void* d_out, int out_size, void* d_ws, size_t ws_size,
                              hipStream_t stream) {
    const float* means2d = (const float*)d_in[0];
    const float* conics  = (const float*)d_in[1];
    const float* colors  = (const float*)d_in[2];
    const float* opac    = (const float*)d_in[3];
    const float* depths  = (const float*)d_in[4];
    float* out = (float*)d_out;

    raster_fused<<<256, 512, 0, stream>>>(means2d, conics, colors, opac, depths, out);
}